// Round 3
// baseline (189.612 us; speedup 1.0000x reference)
//
#include <hip/hip_runtime.h>

// TempCtxAttention — f16 MFMA pipeline, LDS-free attention.
// ws (u16 elements): kp[256*8*128*32] | vt[256*8*32*128] | qp[256*256] | wo16[256*256] | ctx[65536*256]
// total 33,685,504 u16 = 64.25 MB.

typedef unsigned short u16;
typedef unsigned int u32;
typedef __attribute__((ext_vector_type(8))) _Float16 half8;
typedef __attribute__((ext_vector_type(4))) _Float16 half4;
typedef __attribute__((ext_vector_type(4))) float f32x4;
typedef __attribute__((ext_vector_type(4))) unsigned short us4;
typedef __attribute__((ext_vector_type(2))) unsigned int u32x2;

__device__ __forceinline__ u16 f2h(float v) {
  _Float16 h = (_Float16)v;            // v_cvt_f16_f32 (RNE)
  return __builtin_bit_cast(u16, h);
}
__device__ __forceinline__ u32 pk2(float lo, float hi) {   // 2xf16 packed
  return (u32)f2h(lo) | ((u32)f2h(hi) << 16);
}
__device__ __forceinline__ f32x4 mf16(half8 a, half8 b, f32x4 c) {
  return __builtin_amdgcn_mfma_f32_16x16x32_f16(a, b, c, 0, 0, 0);
}
__device__ __forceinline__ f32x4 mf16k16(half4 a, half4 b, f32x4 c) {
  return __builtin_amdgcn_mfma_f32_16x16x16f16(a, b, c, 0, 0, 0);
}

// ---------------- projections ----------------
// MODE 0 additionally converts Wo -> f16 in blocks [16, 80).
template<int MODE>
__global__ __launch_bounds__(256) void proj_kernel(const float* __restrict__ X,
                                                   const float* __restrict__ W,
                                                   const float* __restrict__ bias,
                                                   u16* __restrict__ out,
                                                   const float* __restrict__ Wo,
                                                   u16* __restrict__ wo16) {
  if (MODE == 0 && blockIdx.x >= 16) {
    int i = ((blockIdx.x - 16) * 256 + threadIdx.x) * 4;
    float4 g = *(const float4*)(Wo + i);
    us4 h = { f2h(g.x), f2h(g.y), f2h(g.z), f2h(g.w) };
    *(us4*)(wo16 + i) = h;
    return;
  }
  __shared__ __align__(16) u16 xa[64 * 256];
  __shared__ __align__(16) u16 wa[64 * 256];
  int bid = blockIdx.x;
  int logical;
  if (MODE == 0) {
    logical = bid;
  } else {
    int chunk = gridDim.x >> 3;
    logical = (bid & 7) * chunk + (bid >> 3);
  }
  int rb = logical >> 2, cb = logical & 3;
  int tid = threadIdx.x;

  char* xb = (char*)xa;
  char* wb_ = (char*)wa;
#pragma unroll
  for (int i = 0; i < 16; ++i) {
    int idx = tid + i * 256;
    int row = idx >> 6, c4 = idx & 63;
    int so = (row * 512 + c4 * 8) ^ ((row & 7) << 4);
    float4 gx = *(const float4*)(X + (rb * 64 + row) * 256 + c4 * 4);
    us4 hx = { f2h(gx.x), f2h(gx.y), f2h(gx.z), f2h(gx.w) };
    *(us4*)(xb + so) = hx;
    float4 gw = *(const float4*)(W + (cb * 64 + row) * 256 + c4 * 4);
    us4 hw = { f2h(gw.x), f2h(gw.y), f2h(gw.z), f2h(gw.w) };
    *(us4*)(wb_ + so) = hw;
  }
  __syncthreads();

  int lane = tid & 63, w = tid >> 6;
  int lr = lane & 15, lq = lane >> 4;
  const char* ab = (MODE == 2) ? wb_ : xb;
  const char* bb = (MODE == 2) ? xb : wb_;

  half8 a[8];
#pragma unroll
  for (int kk = 0; kk < 8; ++kk)
    a[kk] = *(const half8*)(ab + (((w * 16 + lr) * 512 + kk * 64 + lq * 16) ^ ((lr & 7) << 4)));

#pragma unroll
  for (int ct = 0; ct < 4; ++ct) {
    f32x4 acc = {0.f, 0.f, 0.f, 0.f};
#pragma unroll
    for (int kk = 0; kk < 8; ++kk) {
      half8 b = *(const half8*)(bb + (((ct * 16 + lr) * 512 + kk * 64 + lq * 16) ^ ((lr & 7) << 4)));
      acc = mf16(a[kk], b, acc);
    }
    if (MODE != 2) {
      int j = cb * 64 + ct * 16 + lr;
      float bj = bias[j];
#pragma unroll
      for (int rr = 0; rr < 4; ++rr) {
        int gr = rb * 64 + w * 16 + lq * 4 + rr;
        float v = acc[rr] + bj;
        if (MODE == 0) {
          out[gr * 256 + j] = f2h(v);
        } else {
          int mm = gr >> 7, kl = gr & 127, hh = j >> 5, d = j & 31;
          out[((mm * 8 + hh) * 128 + kl) * 32 + d] = f2h(v);
        }
      }
    } else {
#pragma unroll
      for (int rr = 0; rr < 4; ++rr) {
        int j = cb * 64 + w * 16 + lq * 4 + rr;
        float v = acc[rr] + bias[j];
        int gr = rb * 64 + ct * 16 + lr;
        int mm = gr >> 7, kl = gr & 127, hh = j >> 5, d = j & 31;
        out[((mm * 8 + hh) * 32 + d) * 128 + kl] = f2h(v);
      }
    }
  }
}

// ---------------- attention -> ctx (f16), LDS-free ----------------
// grid 2048 = 256 m x 4 n-tiles x 2 head-halves (XCD-swizzled: 8 blocks per m on one XCD).
// 4 waves/block, fully independent (no barriers, no LDS).
// S^T = mfma_16x16x32(K, Q): lane holds S^T[kl=kt*16+lq*4+rr][n=lr]  (rr=reg)
// That D-layout == B-frag layout of mfma_16x16x16 (k=lq*4+i), so exp(S) feeds PV directly:
// ctx^T = mfma_16x16x16(V^T, P^T) accumulated over kt.
__global__ __launch_bounds__(256, 6) void attn_ctx_kernel(const u16* __restrict__ qp,
                                                          const u16* __restrict__ kp,
                                                          const u16* __restrict__ vt,
                                                          u16* __restrict__ ctx) {
  int bid = blockIdx.x;
  int xcd = bid & 7, idx = bid >> 3;              // idx in [0,256)
  int m = xcd * 32 + (idx >> 3);
  int sub = idx & 7;
  int nt = sub >> 1, hb = sub & 1;                // n-tile, head-half
  int tid = threadIdx.x;
  int w = tid >> 6, lane = tid & 63;
  int lr = lane & 15, lq = lane >> 4;
  int n = nt * 64 + w * 16 + lr;                  // this lane's n (MFMA col)
  const float SCL2E = 0.25506980508f;             // log2(e)/sqrt(32)

  half8 qa[4];                                    // B-frag: col=n, k=d=lq*8+i
#pragma unroll
  for (int h4 = 0; h4 < 4; ++h4)
    qa[h4] = *(const half8*)(qp + n * 256 + (hb * 4 + h4) * 32 + lq * 8);

#pragma unroll
  for (int h4 = 0; h4 < 4; ++h4) {
    int h = hb * 4 + h4;
    const u16* kh = kp + (m * 8 + h) * 4096;      // [128 kl][32 d]
    const u16* vh = vt + (m * 8 + h) * 4096;      // [32 d][128 kl]
    // ---- scores^T: 8 independent MFMAs ----
    f32x4 s[8];
    __builtin_amdgcn_s_setprio(1);
#pragma unroll
    for (int kt = 0; kt < 8; ++kt) {
      half8 ka = *(const half8*)(kh + (kt * 16 + lr) * 32 + lq * 8);
      f32x4 z = {0.f, 0.f, 0.f, 0.f};
      s[kt] = mf16(ka, qa[h4], z);
    }
    __builtin_amdgcn_s_setprio(0);
    // ---- softmax over kl for column n: 32 local + shfl over lq groups ----
    float mx = s[0][0];
#pragma unroll
    for (int kt = 0; kt < 8; ++kt)
#pragma unroll
      for (int rr = 0; rr < 4; ++rr) mx = fmaxf(mx, s[kt][rr]);
    mx = fmaxf(mx, __shfl_xor(mx, 16));
    mx = fmaxf(mx, __shfl_xor(mx, 32));
    float sum = 0.f;
    half4 pb[8];                                  // P^T B-frags for 16x16x16 PV
#pragma unroll
    for (int kt = 0; kt < 8; ++kt) {
      float p0 = __builtin_amdgcn_exp2f((s[kt][0] - mx) * SCL2E);
      float p1 = __builtin_amdgcn_exp2f((s[kt][1] - mx) * SCL2E);
      float p2 = __builtin_amdgcn_exp2f((s[kt][2] - mx) * SCL2E);
      float p3 = __builtin_amdgcn_exp2f((s[kt][3] - mx) * SCL2E);
      sum += (p0 + p1) + (p2 + p3);
      u32x2 pw = { pk2(p0, p1), pk2(p2, p3) };
      pb[kt] = __builtin_bit_cast(half4, pw);
    }
    sum += __shfl_xor(sum, 16);
    sum += __shfl_xor(sum, 32);
    float inv = 1.0f / sum;                       // deferred normalization
    // ---- PV: ctx^T[d][n] = sum_kt V^T[d][kt-block] * P^T[kt-block][n] ----
    f32x4 acc0 = {0.f, 0.f, 0.f, 0.f};
    f32x4 acc1 = {0.f, 0.f, 0.f, 0.f};
    __builtin_amdgcn_s_setprio(1);
#pragma unroll
    for (int kt = 0; kt < 8; ++kt) {
      half4 va0 = *(const half4*)(vh + lr * 128 + kt * 16 + lq * 4);          // d=lr
      acc0 = mf16k16(va0, pb[kt], acc0);
      half4 va1 = *(const half4*)(vh + (16 + lr) * 128 + kt * 16 + lq * 4);   // d=16+lr
      acc1 = mf16k16(va1, pb[kt], acc1);
    }
    __builtin_amdgcn_s_setprio(0);
    us4 st0 = { f2h(acc0[0] * inv), f2h(acc0[1] * inv), f2h(acc0[2] * inv), f2h(acc0[3] * inv) };
    *(us4*)(ctx + (n * 256 + m) * 256 + h * 32 + lq * 4) = st0;
    us4 st1 = { f2h(acc1[0] * inv), f2h(acc1[1] * inv), f2h(acc1[2] * inv), f2h(acc1[3] * inv) };
    *(us4*)(ctx + (n * 256 + m) * 256 + h * 32 + 16 + lq * 4) = st1;
  }
}

// ---------------- output projection GEMM: out[65536][256] = ctx @ wo^T + bo ----------------
// LDS-free: Wo (128KB) is L2-resident. grid 2048 = 512 rowtiles(BM=128) x 4 coltiles(BN=64),
// XCD-chunked so same-rowtile blocks share ctx in L2. 4 waves (2r x 2c), wave tile 64x32.
__global__ __launch_bounds__(256, 6) void outproj_kernel(const u16* __restrict__ ctx,
                                                         const u16* __restrict__ wo_g,
                                                         const float* __restrict__ bo,
                                                         float* __restrict__ out) {
  int bid = blockIdx.x;
  int logical = (bid & 7) * 256 + (bid >> 3);
  int rt = logical >> 2, ct = logical & 3;
  int tid = threadIdx.x;
  int wv = tid >> 6, lane = tid & 63;
  int lr = lane & 15, lq = lane >> 4;
  int wr = wv >> 1, wc = wv & 1;
  int r0 = rt * 128 + wr * 64;
  int c0 = ct * 64 + wc * 32;

  f32x4 acc[4][2];
#pragma unroll
  for (int mt = 0; mt < 4; ++mt) {
    acc[mt][0] = f32x4{0.f, 0.f, 0.f, 0.f};
    acc[mt][1] = f32x4{0.f, 0.f, 0.f, 0.f};
  }

  __builtin_amdgcn_s_setprio(1);
#pragma unroll
  for (int kk = 0; kk < 8; ++kk) {
    half8 b0 = *(const half8*)(wo_g + (c0 + lr) * 256 + kk * 32 + lq * 8);
    half8 b1 = *(const half8*)(wo_g + (c0 + 16 + lr) * 256 + kk * 32 + lq * 8);
#pragma unroll
    for (int mt = 0; mt < 4; ++mt) {
      half8 a = *(const half8*)(ctx + (r0 + mt * 16 + lr) * 256 + kk * 32 + lq * 8);
      acc[mt][0] = mf16(a, b0, acc[mt][0]);
      acc[mt][1] = mf16(a, b1, acc[mt][1]);
    }
  }
  __builtin_amdgcn_s_setprio(0);

#pragma unroll
  for (int ntl = 0; ntl < 2; ++ntl) {
    int j = c0 + ntl * 16 + lr;
    float bj = bo[j];
#pragma unroll
    for (int mt = 0; mt < 4; ++mt)
#pragma unroll
      for (int rr = 0; rr < 4; ++rr)
        out[(r0 + mt * 16 + lq * 4 + rr) * 256 + j] = acc[mt][ntl][rr] + bj;
  }
}

extern "C" void kernel_launch(void* const* d_in, const int* in_sizes, int n_in,
                              void* d_out, int out_size, void* d_ws, size_t ws_size,
                              hipStream_t stream) {
  (void)in_sizes; (void)n_in; (void)out_size; (void)ws_size;
  const float* query = (const float*)d_in[0];
  const float* key   = (const float*)d_in[1];
  const float* value = (const float*)d_in[2];
  const float* Wq = (const float*)d_in[3];
  const float* bq = (const float*)d_in[4];
  const float* Wk = (const float*)d_in[5];
  const float* bk = (const float*)d_in[6];
  const float* Wv = (const float*)d_in[7];
  const float* bv = (const float*)d_in[8];
  const float* Wo = (const float*)d_in[9];
  const float* bo = (const float*)d_in[10];
  float* out = (float*)d_out;

  u16* ws = (u16*)d_ws;
  u16* kp   = ws;                  // [256*8][128][32]
  u16* vt   = kp + 8388608;        // [256*8][32][128]
  u16* qp   = vt + 8388608;        // [256][256]
  u16* wo16 = qp + 65536;          // [256][256]
  u16* ctx  = wo16 + 65536;        // [65536][256]

  proj_kernel<0><<<80,   256, 0, stream>>>(query, Wq, bq, qp, Wo, wo16);
  proj_kernel<1><<<2048, 256, 0, stream>>>(key,   Wk, bk, kp, nullptr, nullptr);
  proj_kernel<2><<<2048, 256, 0, stream>>>(value, Wv, bv, vt, nullptr, nullptr);
  attn_ctx_kernel<<<2048, 256, 0, stream>>>(qp, kp, vt, ctx);
  outproj_kernel<<<2048, 256, 0, stream>>>(ctx, wo16, bo, out);
}

// Round 4
// 129.772 us; speedup vs baseline: 1.4611x; 1.4611x over previous
//
#include <hip/hip_runtime.h>

// TempCtxAttention — fully fused f16 MFMA pipeline.
// ws (u16): kp[256*8*4096] | vt3[256*8*4096] | qp[256*256] | wof[256*256]  = 33.8 MB
// kp : K rows       [m][h][kl][d]                       (QK A-frags, coalesced)
// vt3: V^T K=16 A-frags [m][h][jt(2)][kt(8)][lane(64)]x4
// wof: Wo K=16 A-frag pairs [h][jtile(16)][lane(64)][jt0:4|jt1:4]
// Fused kernel: QK^T(swapped) -> softmax -> PV -> out-projection, all in registers.

typedef unsigned short u16;
typedef unsigned int u32;
typedef __attribute__((ext_vector_type(8))) _Float16 half8;
typedef __attribute__((ext_vector_type(4))) _Float16 half4;
typedef __attribute__((ext_vector_type(4))) float f32x4;
typedef __attribute__((ext_vector_type(4))) unsigned short us4;
typedef __attribute__((ext_vector_type(2))) unsigned int u32x2;

__device__ __forceinline__ u16 f2h(float v) {
  _Float16 h = (_Float16)v;
  return __builtin_bit_cast(u16, h);
}
__device__ __forceinline__ u32 pk2(float lo, float hi) {
  return (u32)f2h(lo) | ((u32)f2h(hi) << 16);
}
__device__ __forceinline__ f32x4 mf16(half8 a, half8 b, f32x4 c) {
  return __builtin_amdgcn_mfma_f32_16x16x32_f16(a, b, c, 0, 0, 0);
}
__device__ __forceinline__ f32x4 mf16k16(half4 a, half4 b, f32x4 c) {
  return __builtin_amdgcn_mfma_f32_16x16x16f16(a, b, c, 0, 0, 0);
}

// ---------------- projections ----------------
// MODE 0: q-proj (blocks 0-15) + Wo->wof fragment conversion (blocks 16-79).
// MODE 1: k-proj -> kp[((m*8+h)*128+kl)*32+d]
// MODE 2: v-proj (transposed compute) -> vt3 pre-fragmented K=16 A-frags
template<int MODE>
__global__ __launch_bounds__(256) void proj_kernel(const float* __restrict__ X,
                                                   const float* __restrict__ W,
                                                   const float* __restrict__ bias,
                                                   u16* __restrict__ out,
                                                   const float* __restrict__ Wo,
                                                   u16* __restrict__ wof) {
  if (MODE == 0 && blockIdx.x >= 16) {
    // Wo[j][d] -> wof: t = ((h*16+jtile)*64+ln)*2 + jt ; write 4 u16 at wof+t*4
    int t = (blockIdx.x - 16) * 256 + threadIdx.x;          // [0,16384)
    int jt = t & 1, ln = (t >> 1) & 63, jtile = (t >> 7) & 15, h = t >> 11;
    int j = jtile * 16 + (ln & 15);
    int d0 = h * 32 + jt * 16 + (ln >> 4) * 4;
    float4 g = *(const float4*)(Wo + j * 256 + d0);
    us4 hv = { f2h(g.x), f2h(g.y), f2h(g.z), f2h(g.w) };
    *(us4*)(wof + t * 4) = hv;
    return;
  }
  __shared__ __align__(16) u16 xa[64 * 256];
  __shared__ __align__(16) u16 wa[64 * 256];
  int bid = blockIdx.x;
  int logical;
  if (MODE == 0) {
    logical = bid;
  } else {
    int chunk = gridDim.x >> 3;
    logical = (bid & 7) * chunk + (bid >> 3);
  }
  int rb = logical >> 2, cb = logical & 3;
  int tid = threadIdx.x;

  char* xb = (char*)xa;
  char* wb_ = (char*)wa;
#pragma unroll
  for (int i = 0; i < 16; ++i) {
    int idx = tid + i * 256;
    int row = idx >> 6, c4 = idx & 63;
    int so = (row * 512 + c4 * 8) ^ ((row & 7) << 4);
    float4 gx = *(const float4*)(X + (rb * 64 + row) * 256 + c4 * 4);
    us4 hx = { f2h(gx.x), f2h(gx.y), f2h(gx.z), f2h(gx.w) };
    *(us4*)(xb + so) = hx;
    float4 gw = *(const float4*)(W + (cb * 64 + row) * 256 + c4 * 4);
    us4 hw = { f2h(gw.x), f2h(gw.y), f2h(gw.z), f2h(gw.w) };
    *(us4*)(wb_ + so) = hw;
  }
  __syncthreads();

  int lane = tid & 63, w = tid >> 6;
  int lr = lane & 15, lq = lane >> 4;
  const char* ab = (MODE == 2) ? wb_ : xb;
  const char* bb = (MODE == 2) ? xb : wb_;

  half8 a[8];
#pragma unroll
  for (int kk = 0; kk < 8; ++kk)
    a[kk] = *(const half8*)(ab + (((w * 16 + lr) * 512 + kk * 64 + lq * 16) ^ ((lr & 7) << 4)));

#pragma unroll
  for (int ct = 0; ct < 4; ++ct) {
    f32x4 acc = {0.f, 0.f, 0.f, 0.f};
#pragma unroll
    for (int kk = 0; kk < 8; ++kk) {
      half8 b = *(const half8*)(bb + (((ct * 16 + lr) * 512 + kk * 64 + lq * 16) ^ ((lr & 7) << 4)));
      acc = mf16(a[kk], b, acc);
    }
    if (MODE != 2) {
      int j = cb * 64 + ct * 16 + lr;
      float bj = bias[j];
#pragma unroll
      for (int rr = 0; rr < 4; ++rr) {
        int gr = rb * 64 + w * 16 + lq * 4 + rr;
        float v = acc[rr] + bj;
        if (MODE == 0) {
          out[gr * 256 + j] = f2h(v);
        } else {
          int mm = gr >> 7, kl = gr & 127, hh = j >> 5, d = j & 31;
          out[((mm * 8 + hh) * 128 + kl) * 32 + d] = f2h(v);
        }
      }
    } else {
      // D[j][gr]: j = output channel (row), gr = m*128+kl (col)
#pragma unroll
      for (int rr = 0; rr < 4; ++rr) {
        int j = cb * 64 + w * 16 + lq * 4 + rr;
        float v = acc[rr] + bias[j];
        int gr = rb * 64 + ct * 16 + lr;
        int mm = gr >> 7, kl = gr & 127, hh = j >> 5, d = j & 31;
        int jt = d >> 4, lrp = d & 15, kt = kl >> 4, lqp = (kl >> 2) & 3, e = kl & 3;
        out[(((mm * 8 + hh) * 2 + jt) * 8 + kt) * 256 + (lqp * 16 + lrp) * 4 + e] = f2h(v);
      }
    }
  }
}

// ---------------- fused attention + output projection ----------------
// grid 1024 = 256 m x 4 n-tiles (XCD-swizzled: 4 blocks/m share one XCD L2).
// 4 waves/block, fully independent; no LDS, no barriers.
// Per head: S^T = mfma16x16x32(K,Q) -> softmax (2 shfl) -> P^T feeds PV directly as
// B-frags (K=16) -> ctx^T D-frags feed out-proj directly as B-frags (K=16),
// accumulated over all heads in accO[16] (f32).
__global__ __launch_bounds__(256, 4) void fused_attn_kernel(const u16* __restrict__ qp,
                                                            const u16* __restrict__ kp,
                                                            const u16* __restrict__ vt3,
                                                            const u16* __restrict__ wof,
                                                            const float* __restrict__ bo,
                                                            float* __restrict__ out) {
  int bid = blockIdx.x;
  int xcd = bid & 7, idx = bid >> 3;              // idx in [0,128)
  int m = xcd * 32 + (idx >> 2);
  int nt = idx & 3;
  int tid = threadIdx.x;
  int w = tid >> 6, lane = tid & 63;
  int lr = lane & 15, lq = lane >> 4;
  int n = nt * 64 + w * 16 + lr;
  const float SCL2E = 0.25506980508f;             // log2(e)/sqrt(32)

  f32x4 accO[16];
#pragma unroll
  for (int jt2 = 0; jt2 < 16; ++jt2) accO[jt2] = f32x4{0.f, 0.f, 0.f, 0.f};

#pragma unroll
  for (int h = 0; h < 8; ++h) {
    const u16* kh = kp + (m * 8 + h) * 4096;
    const u16* vh = vt3 + (m * 8 + h) * 4096;
    half8 qa = *(const half8*)(qp + n * 256 + h * 32 + lq * 8);
    // ---- scores^T ----
    f32x4 s[8];
    __builtin_amdgcn_s_setprio(1);
#pragma unroll
    for (int kt = 0; kt < 8; ++kt) {
      half8 ka = *(const half8*)(kh + (kt * 16 + lr) * 32 + lq * 8);   // 1KB coalesced
      f32x4 z = {0.f, 0.f, 0.f, 0.f};
      s[kt] = mf16(ka, qa, z);
    }
    __builtin_amdgcn_s_setprio(0);
    // ---- softmax over kl (column n): 31 local max + 2 shfl ----
    float mx = s[0][0];
#pragma unroll
    for (int kt = 0; kt < 8; ++kt)
#pragma unroll
      for (int rr = 0; rr < 4; ++rr) mx = fmaxf(mx, s[kt][rr]);
    mx = fmaxf(mx, __shfl_xor(mx, 16));
    mx = fmaxf(mx, __shfl_xor(mx, 32));
    float sum = 0.f;
    half4 pb[8];                                  // unnormalized P^T B-frags
#pragma unroll
    for (int kt = 0; kt < 8; ++kt) {
      float p0 = __builtin_amdgcn_exp2f((s[kt][0] - mx) * SCL2E);
      float p1 = __builtin_amdgcn_exp2f((s[kt][1] - mx) * SCL2E);
      float p2 = __builtin_amdgcn_exp2f((s[kt][2] - mx) * SCL2E);
      float p3 = __builtin_amdgcn_exp2f((s[kt][3] - mx) * SCL2E);
      sum += (p0 + p1) + (p2 + p3);
      u32x2 pw = { pk2(p0, p1), pk2(p2, p3) };
      pb[kt] = __builtin_bit_cast(half4, pw);
    }
    sum += __shfl_xor(sum, 16);
    sum += __shfl_xor(sum, 32);
    float inv = 1.0f / sum;
    // ---- PV: ctx^T = V^T @ P^T, pre-fragmented V loads (512B coalesced) ----
    f32x4 a0 = {0.f, 0.f, 0.f, 0.f};
    f32x4 a1 = {0.f, 0.f, 0.f, 0.f};
    __builtin_amdgcn_s_setprio(1);
#pragma unroll
    for (int kt = 0; kt < 8; ++kt) {
      half4 va0 = *(const half4*)(vh + (kt << 8) + (lane << 2));
      a0 = mf16k16(va0, pb[kt], a0);
      half4 va1 = *(const half4*)(vh + 2048 + (kt << 8) + (lane << 2));
      a1 = mf16k16(va1, pb[kt], a1);
    }
    __builtin_amdgcn_s_setprio(0);
    // normalize + pack ctx^T D-frags -> B-frags for out-proj
    u32x2 pw0 = { pk2(a0[0] * inv, a0[1] * inv), pk2(a0[2] * inv, a0[3] * inv) };
    half4 pbo0 = __builtin_bit_cast(half4, pw0);
    u32x2 pw1 = { pk2(a1[0] * inv, a1[1] * inv), pk2(a1[2] * inv, a1[3] * inv) };
    half4 pbo1 = __builtin_bit_cast(half4, pw1);
    // ---- out^T[j][n] += Wo_frag(h) x ctx_frag(h): 32 MFMAs, 1KB-coalesced Wo loads ----
    __builtin_amdgcn_s_setprio(1);
#pragma unroll
    for (int jt2 = 0; jt2 < 16; ++jt2) {
      half8 wv = *(const half8*)(wof + ((h * 16 + jt2) * 64 + lane) * 8);
      half4 wlo = __builtin_shufflevector(wv, wv, 0, 1, 2, 3);
      half4 whi = __builtin_shufflevector(wv, wv, 4, 5, 6, 7);
      accO[jt2] = mf16k16(wlo, pbo0, accO[jt2]);
      accO[jt2] = mf16k16(whi, pbo1, accO[jt2]);
    }
    __builtin_amdgcn_s_setprio(0);
  }
  // ---- epilogue: out[(n*256+m)*256 + j] = accO + bo, full-row coalesced float4 ----
  float* orow = out + (n * 256 + m) * 256;
#pragma unroll
  for (int jt2 = 0; jt2 < 16; ++jt2) {
    float4 bv = *(const float4*)(bo + jt2 * 16 + lq * 4);
    float4 r;
    r.x = accO[jt2][0] + bv.x;
    r.y = accO[jt2][1] + bv.y;
    r.z = accO[jt2][2] + bv.z;
    r.w = accO[jt2][3] + bv.w;
    *(float4*)(orow + jt2 * 16 + lq * 4) = r;
  }
}

extern "C" void kernel_launch(void* const* d_in, const int* in_sizes, int n_in,
                              void* d_out, int out_size, void* d_ws, size_t ws_size,
                              hipStream_t stream) {
  (void)in_sizes; (void)n_in; (void)out_size; (void)ws_size;
  const float* query = (const float*)d_in[0];
  const float* key   = (const float*)d_in[1];
  const float* value = (const float*)d_in[2];
  const float* Wq = (const float*)d_in[3];
  const float* bq = (const float*)d_in[4];
  const float* Wk = (const float*)d_in[5];
  const float* bk = (const float*)d_in[6];
  const float* Wv = (const float*)d_in[7];
  const float* bv = (const float*)d_in[8];
  const float* Wo = (const float*)d_in[9];
  const float* bo = (const float*)d_in[10];
  float* out = (float*)d_out;

  u16* ws = (u16*)d_ws;
  u16* kp  = ws;                  // [256*8][128][32]
  u16* vt3 = kp + 8388608;        // [256*8][2][8][64][4]
  u16* qp  = vt3 + 8388608;       // [256][256]
  u16* wof = qp + 65536;          // [8][16][64][8]

  proj_kernel<0><<<80,   256, 0, stream>>>(query, Wq, bq, qp, Wo, wof);
  proj_kernel<1><<<2048, 256, 0, stream>>>(key,   Wk, bk, kp, nullptr, nullptr);
  proj_kernel<2><<<2048, 256, 0, stream>>>(value, Wv, bv, vt3, nullptr, nullptr);
  fused_attn_kernel<<<1024, 256, 0, stream>>>(qp, kp, vt3, wof, bo, out);
}

// Round 6
// 85.795 us; speedup vs baseline: 2.2101x; 1.5126x over previous
//
#include <hip/hip_runtime.h>

// TempCtxAttention — f16 MFMA, LDS-pipelined fused kernel.
// ws (u16): kfrag[256*8*4096] | vt3[256*8*4096] | qp[256*256] | wof[256*256] = 33.8 MB
// kfrag: QK A-frags   [m][h][kt(8)][lane(64)][8]   (lane = (d>>3)*16 + (kl&15))
// vt3 : PV A-frags    [m][h][jt(2)][kt(8)][lane(64)][4]
// wof : outproj K=32 A-frags [h][jtile(16)][lane(64)][8]  (lane ln: j=jtile*16+(ln&15), d=h*32+(ln>>4)*8+0..7)

typedef unsigned short u16;
typedef unsigned int u32;
typedef __attribute__((ext_vector_type(8))) _Float16 half8;
typedef __attribute__((ext_vector_type(4))) _Float16 half4;
typedef __attribute__((ext_vector_type(4))) float f32x4;
typedef __attribute__((ext_vector_type(4))) unsigned short us4;
typedef __attribute__((ext_vector_type(2))) unsigned int u32x2;

__device__ __forceinline__ u16 f2h(float v) {
  _Float16 h = (_Float16)v;
  return __builtin_bit_cast(u16, h);
}
__device__ __forceinline__ u32 pk2(float lo, float hi) {
  return (u32)f2h(lo) | ((u32)f2h(hi) << 16);
}
__device__ __forceinline__ f32x4 mf16(half8 a, half8 b, f32x4 c) {
  return __builtin_amdgcn_mfma_f32_16x16x32_f16(a, b, c, 0, 0, 0);
}
__device__ __forceinline__ f32x4 mf16k16(half4 a, half4 b, f32x4 c) {
  return __builtin_amdgcn_mfma_f32_16x16x16f16(a, b, c, 0, 0, 0);
}
__device__ __forceinline__ void gload_lds16(const void* g, void* l) {
  __builtin_amdgcn_global_load_lds((const __attribute__((address_space(1))) u32*)g,
                                   (__attribute__((address_space(3))) u32*)l, 16, 0, 0);
}

// ---------------- projections ----------------
// MODE 0: q-proj (blocks 0-15) + Wo->wof K=32 A-frag conversion (blocks 16-47).
// MODE 1: k-proj -> kfrag pre-fragmented
// MODE 2: v-proj (transposed compute) -> vt3 pre-fragmented
template<int MODE>
__global__ __launch_bounds__(256) void proj_kernel(const float* __restrict__ X,
                                                   const float* __restrict__ W,
                                                   const float* __restrict__ bias,
                                                   u16* __restrict__ out,
                                                   const float* __restrict__ Wo,
                                                   u16* __restrict__ wof) {
  if (MODE == 0 && blockIdx.x >= 16) {
    // K=32 A-frag: entry t = (h*16+jtile)*64+ln holds Wo[j][d0..d0+8)
    int t = (blockIdx.x - 16) * 256 + threadIdx.x;          // [0, 8192)
    int ln = t & 63, jtile = (t >> 6) & 15, h = t >> 10;
    int j = jtile * 16 + (ln & 15);
    int d0 = h * 32 + (ln >> 4) * 8;
    float4 g0 = *(const float4*)(Wo + j * 256 + d0);
    float4 g1 = *(const float4*)(Wo + j * 256 + d0 + 4);
    us4 h0 = { f2h(g0.x), f2h(g0.y), f2h(g0.z), f2h(g0.w) };
    us4 h1 = { f2h(g1.x), f2h(g1.y), f2h(g1.z), f2h(g1.w) };
    *(us4*)(wof + t * 8) = h0;
    *(us4*)(wof + t * 8 + 4) = h1;
    return;
  }
  __shared__ __align__(16) u16 xa[64 * 256];
  __shared__ __align__(16) u16 wa[64 * 256];
  int bid = blockIdx.x;
  int logical;
  if (MODE == 0) {
    logical = bid;
  } else {
    int chunk = gridDim.x >> 3;
    logical = (bid & 7) * chunk + (bid >> 3);
  }
  int rb = logical >> 2, cb = logical & 3;
  int tid = threadIdx.x;

  char* xb = (char*)xa;
  char* wb_ = (char*)wa;
#pragma unroll
  for (int i = 0; i < 16; ++i) {
    int idx = tid + i * 256;
    int row = idx >> 6, c4 = idx & 63;
    int so = (row * 512 + c4 * 8) ^ ((row & 7) << 4);
    float4 gx = *(const float4*)(X + (rb * 64 + row) * 256 + c4 * 4);
    us4 hx = { f2h(gx.x), f2h(gx.y), f2h(gx.z), f2h(gx.w) };
    *(us4*)(xb + so) = hx;
    float4 gw = *(const float4*)(W + (cb * 64 + row) * 256 + c4 * 4);
    us4 hw = { f2h(gw.x), f2h(gw.y), f2h(gw.z), f2h(gw.w) };
    *(us4*)(wb_ + so) = hw;
  }
  __syncthreads();

  int lane = tid & 63, w = tid >> 6;
  int lr = lane & 15, lq = lane >> 4;
  const char* ab = (MODE == 2) ? wb_ : xb;
  const char* bb = (MODE == 2) ? xb : wb_;

  half8 a[8];
#pragma unroll
  for (int kk = 0; kk < 8; ++kk)
    a[kk] = *(const half8*)(ab + (((w * 16 + lr) * 512 + kk * 64 + lq * 16) ^ ((lr & 7) << 4)));

#pragma unroll
  for (int ct = 0; ct < 4; ++ct) {
    f32x4 acc = {0.f, 0.f, 0.f, 0.f};
#pragma unroll
    for (int kk = 0; kk < 8; ++kk) {
      half8 b = *(const half8*)(bb + (((ct * 16 + lr) * 512 + kk * 64 + lq * 16) ^ ((lr & 7) << 4)));
      acc = mf16(a[kk], b, acc);
    }
    if (MODE != 2) {
      int j = cb * 64 + ct * 16 + lr;
      float bj = bias[j];
#pragma unroll
      for (int rr = 0; rr < 4; ++rr) {
        int gr = rb * 64 + w * 16 + lq * 4 + rr;
        float v = acc[rr] + bj;
        if (MODE == 0) {
          out[gr * 256 + j] = f2h(v);
        } else {
          int mm = gr >> 7, kl = gr & 127, hh = j >> 5, d = j & 31;
          // kfrag scatter: [m][h][kt][lane=(d>>3)*16+(kl&15)][d&7]
          out[(mm * 8 + hh) * 4096 + (kl >> 4) * 512 + ((d >> 3) * 16 + (kl & 15)) * 8 + (d & 7)] = f2h(v);
        }
      }
    } else {
#pragma unroll
      for (int rr = 0; rr < 4; ++rr) {
        int j = cb * 64 + w * 16 + lq * 4 + rr;
        float v = acc[rr] + bias[j];
        int gr = rb * 64 + ct * 16 + lr;
        int mm = gr >> 7, kl = gr & 127, hh = j >> 5, d = j & 31;
        int jt = d >> 4, lrp = d & 15, kt = kl >> 4, lqp = (kl >> 2) & 3, e = kl & 3;
        out[(((mm * 8 + hh) * 2 + jt) * 8 + kt) * 256 + (lqp * 16 + lrp) * 4 + e] = f2h(v);
      }
    }
  }
}

// ---------------- fused attention + output projection (LDS pipeline) ----------------
// grid 512 = 256 m x 2 n-halves (XCD-paired). 8 waves/block, barrier-synced per head.
// Per head: [stage K/V h+1 via global_load_lds] QK(S^T) -> reg softmax -> PV -> ctx
// frags to LDS -> barrier -> out-proj (wave owns 32 j's, all 128 n), accO += .
__global__ __launch_bounds__(512, 4) void fused_attn_kernel(const u16* __restrict__ qp,
                                                            const u16* __restrict__ kp,
                                                            const u16* __restrict__ vt3,
                                                            const u16* __restrict__ wof,
                                                            const float* __restrict__ bo,
                                                            float* __restrict__ out) {
  __shared__ __align__(16) u16 kbuf[2][4096];   // per-head QK A-frags, dbuf
  __shared__ __align__(16) u16 vbuf[2][4096];   // per-head PV A-frags, dbuf
  __shared__ __align__(16) u16 cbuf[2][4096];   // per-head ctx B-frags [nb][lane][8], dbuf

  const int bid = blockIdx.x;
  const int xcd = bid & 7, idx = bid >> 3;
  const int m = xcd * 32 + (idx >> 1);
  const int nh = idx & 1;
  const int tid = threadIdx.x;
  const int w = tid >> 6, lane = tid & 63;
  const int lr = lane & 15, lq = lane >> 4;
  const int n0 = nh * 128 + w * 16;
  const float SCL2E = 0.25506980508f;           // log2(e)/sqrt(32)

  const char* kg = (const char*)(kp + m * 8 * 4096);   // 8KB per head
  const char* vg = (const char*)(vt3 + m * 8 * 4096);

  // prologue: stage head 0 (each wave DMAs 1KB of K and 1KB of V)
  gload_lds16(kg + w * 1024 + lane * 16, (char*)(&kbuf[0][0]) + w * 1024);
  gload_lds16(vg + w * 1024 + lane * 16, (char*)(&vbuf[0][0]) + w * 1024);
  __syncthreads();

  f32x4 accO[2][8];
#pragma unroll
  for (int jt = 0; jt < 2; ++jt)
#pragma unroll
    for (int nb = 0; nb < 8; ++nb) accO[jt][nb] = f32x4{0.f, 0.f, 0.f, 0.f};

  for (int h = 0; h < 8; ++h) {
    const int cur = h & 1;
    char* kb = (char*)(&kbuf[cur][0]);
    char* vb = (char*)(&vbuf[cur][0]);
    char* cb = (char*)(&cbuf[cur][0]);
    if (h < 7) {   // stage next head; drained by this head's __syncthreads
      gload_lds16(kg + (h + 1) * 8192 + w * 1024 + lane * 16, (char*)(&kbuf[cur ^ 1][0]) + w * 1024);
      gload_lds16(vg + (h + 1) * 8192 + w * 1024 + lane * 16, (char*)(&vbuf[cur ^ 1][0]) + w * 1024);
    }
    half8 qa = *(const half8*)(qp + (n0 + lr) * 256 + h * 32 + lq * 8);
    // ---- scores^T: lane holds S^T[kl=kt*16+lq*4+rr][n=n0+lr] ----
    f32x4 s[8];
    __builtin_amdgcn_s_setprio(1);
#pragma unroll
    for (int kt = 0; kt < 8; ++kt) {
      half8 ka = *(const half8*)(kb + kt * 1024 + lane * 16);   // lane-linear b128
      f32x4 z = {0.f, 0.f, 0.f, 0.f};
      s[kt] = mf16(ka, qa, z);
    }
    __builtin_amdgcn_s_setprio(0);
    // ---- softmax over kl (parallel-tree max/sum + 2 shfl) ----
    f32x4 m4 = s[0];
#pragma unroll
    for (int kt = 1; kt < 8; ++kt) {
      m4[0] = fmaxf(m4[0], s[kt][0]);
      m4[1] = fmaxf(m4[1], s[kt][1]);
      m4[2] = fmaxf(m4[2], s[kt][2]);
      m4[3] = fmaxf(m4[3], s[kt][3]);
    }
    float mx = fmaxf(fmaxf(m4[0], m4[1]), fmaxf(m4[2], m4[3]));
    mx = fmaxf(mx, __shfl_xor(mx, 16));
    mx = fmaxf(mx, __shfl_xor(mx, 32));
    float sA = 0.f, sB = 0.f;
    half4 pb[8];
#pragma unroll
    for (int kt = 0; kt < 8; ++kt) {
      float p0 = __builtin_amdgcn_exp2f((s[kt][0] - mx) * SCL2E);
      float p1 = __builtin_amdgcn_exp2f((s[kt][1] - mx) * SCL2E);
      float p2 = __builtin_amdgcn_exp2f((s[kt][2] - mx) * SCL2E);
      float p3 = __builtin_amdgcn_exp2f((s[kt][3] - mx) * SCL2E);
      sA += p0 + p1; sB += p2 + p3;
      u32x2 pw = { pk2(p0, p1), pk2(p2, p3) };
      pb[kt] = __builtin_bit_cast(half4, pw);
    }
    float sum = sA + sB;
    sum += __shfl_xor(sum, 16);
    sum += __shfl_xor(sum, 32);
    float inv = 1.0f / sum;
    // ---- PV: ctx^T[d][n], K=16 MFMAs, lane-linear b64 V reads ----
    f32x4 a0 = {0.f, 0.f, 0.f, 0.f}, a1 = {0.f, 0.f, 0.f, 0.f};
    __builtin_amdgcn_s_setprio(1);
#pragma unroll
    for (int kt = 0; kt < 8; ++kt) {
      half4 v0 = *(const half4*)(vb + kt * 512 + lane * 8);
      a0 = mf16k16(v0, pb[kt], a0);
      half4 v1 = *(const half4*)(vb + 4096 + kt * 512 + lane * 8);
      a1 = mf16k16(v1, pb[kt], a1);
    }
    __builtin_amdgcn_s_setprio(0);
    // ---- ctx frags (normalized f16) -> LDS in outproj K=32 B-frag layout ----
    u32x2 c0 = { pk2(a0[0] * inv, a0[1] * inv), pk2(a0[2] * inv, a0[3] * inv) };
    u32x2 c1 = { pk2(a1[0] * inv, a1[1] * inv), pk2(a1[2] * inv, a1[3] * inv) };
    const int cwo = w * 1024 + ((lq >> 1) * 16 + lr) * 16 + (lq & 1) * 8;
    *(u32x2*)(cb + cwo) = c0;          // d = lq*4..+4
    *(u32x2*)(cb + cwo + 512) = c1;    // d = 16+lq*4..+4
    __syncthreads();                   // ctx visible + stage(h+1) drained (vmcnt0)
    // ---- out-proj: this wave's 32 j's x all 128 n, K=32/head ----
    half8 wv0 = *(const half8*)(wof + ((h * 16 + w * 2 + 0) * 64 + lane) * 8);
    half8 wv1 = *(const half8*)(wof + ((h * 16 + w * 2 + 1) * 64 + lane) * 8);
    __builtin_amdgcn_s_setprio(1);
#pragma unroll
    for (int nb = 0; nb < 8; ++nb) {
      half8 cf = *(const half8*)(cb + nb * 1024 + lane * 16);   // lane-linear b128
      accO[0][nb] = mf16(wv0, cf, accO[0][nb]);
      accO[1][nb] = mf16(wv1, cf, accO[1][nb]);
    }
    __builtin_amdgcn_s_setprio(0);
  }
  // ---- epilogue: out[(n*256+m)*256 + j], j = w*32+jt*16+lq*4+rr, n = nh*128+nb*16+lr ----
#pragma unroll
  for (int jt = 0; jt < 2; ++jt) {
    const int j0 = w * 32 + jt * 16 + lq * 4;
    float4 bv = *(const float4*)(bo + j0);
#pragma unroll
    for (int nb = 0; nb < 8; ++nb) {
      const int n = nh * 128 + nb * 16 + lr;
      float4 r;
      r.x = accO[jt][nb][0] + bv.x;
      r.y = accO[jt][nb][1] + bv.y;
      r.z = accO[jt][nb][2] + bv.z;
      r.w = accO[jt][nb][3] + bv.w;
      *(float4*)(out + (n * 256 + m) * 256 + j0) = r;
    }
  }
}

extern "C" void kernel_launch(void* const* d_in, const int* in_sizes, int n_in,
                              void* d_out, int out_size, void* d_ws, size_t ws_size,
                              hipStream_t stream) {
  (void)in_sizes; (void)n_in; (void)out_size; (void)ws_size;
  const float* query = (const float*)d_in[0];
  const float* key   = (const float*)d_in[1];
  const float* value = (const float*)d_in[2];
  const float* Wq = (const float*)d_in[3];
  const float* bq = (const float*)d_in[4];
  const float* Wk = (const float*)d_in[5];
  const float* bk = (const float*)d_in[6];
  const float* Wv = (const float*)d_in[7];
  const float* bv = (const float*)d_in[8];
  const float* Wo = (const float*)d_in[9];
  const float* bo = (const float*)d_in[10];
  float* out = (float*)d_out;

  u16* ws = (u16*)d_ws;
  u16* kp  = ws;                  // kfrag [256*8][8][64][8]
  u16* vt3 = kp + 8388608;        // vfrag [256*8][2][8][64][4]
  u16* qp  = vt3 + 8388608;       // [256][256]
  u16* wof = qp + 65536;          // [8][16][64][8]

  proj_kernel<0><<<48,   256, 0, stream>>>(query, Wq, bq, qp, Wo, wof);
  proj_kernel<1><<<2048, 256, 0, stream>>>(key,   Wk, bk, kp, nullptr, nullptr);
  proj_kernel<2><<<2048, 256, 0, stream>>>(value, Wv, bv, vt3, nullptr, nullptr);
  fused_attn_kernel<<<512, 512, 0, stream>>>(qp, kp, vt3, wof, bo, out);
}